// Round 6
// baseline (690.679 us; speedup 1.0000x reference)
//
#include <hip/hip_runtime.h>
#include <math.h>

#define NN 100000
#define NE 1600000
#define SCAN_B 1024
#define SCAN_NB ((NN + SCAN_B - 1) / SCAN_B)   // 98
#define BUCKETS ((NN + 255) >> 8)              // 391 buckets of 256 nodes
#define RVPT 16                                 // edges per thread in reorder

__device__ inline float bsf(unsigned short u) { return __uint_as_float(((unsigned)u) << 16); }
__device__ inline unsigned short f2bs(float f) {           // RNE, matches np/hw bf16
    unsigned u = __float_as_uint(f);
    return (unsigned short)((u + 0x7fffu + ((u >> 16) & 1u)) >> 16);
}

// ---------------- CSR build ----------------
// per-node counts (cursor) + per-bucket histogram
__global__ __launch_bounds__(256) void count_k(const int* __restrict__ dst,
                                               int* __restrict__ cnt,
                                               int* __restrict__ bhist) {
    __shared__ int bh[BUCKETS];
    for (int i = threadIdx.x; i < BUCKETS; i += 256) bh[i] = 0;
    __syncthreads();
    int e = blockIdx.x * 256 + threadIdx.x;
    if (e < NE) {
        int d = dst[e];
        atomicAdd(&cnt[d], 1);
        atomicAdd(&bh[d >> 8], 1);
    }
    __syncthreads();
    for (int i = threadIdx.x; i < BUCKETS; i += 256)
        if (bh[i]) atomicAdd(&bhist[i], bh[i]);
}

// pass 1: per-block exclusive scan of cnt -> row_ptr (local), block totals -> bsum
__global__ __launch_bounds__(SCAN_B) void scan1_k(const int* __restrict__ cnt,
                                                  int* __restrict__ row_ptr,
                                                  int* __restrict__ bsum) {
    __shared__ int wsum[16];
    int tid = threadIdx.x;
    int i = blockIdx.x * SCAN_B + tid;
    int v = (i < NN) ? cnt[i] : 0;
    int lane = tid & 63, wid = tid >> 6;
    int s = v;
#pragma unroll
    for (int off = 1; off < 64; off <<= 1) {
        int t = __shfl_up(s, off);
        if (lane >= off) s += t;
    }
    if (lane == 63) wsum[wid] = s;
    __syncthreads();
    if (wid == 0) {
        int w = (lane < 16) ? wsum[lane] : 0;
#pragma unroll
        for (int off = 1; off < 16; off <<= 1) {
            int t = __shfl_up(w, off);
            if (lane >= off) w += t;
        }
        if (lane < 16) wsum[lane] = w;
    }
    __syncthreads();
    int incl = s + (wid > 0 ? wsum[wid - 1] : 0);
    if (i < NN) row_ptr[i] = incl - v;          // local exclusive
    if (tid == SCAN_B - 1) bsum[blockIdx.x] = wsum[15];  // block total
}

// pass 2: single wave scans block sums (exclusive, in place), total -> row_ptr[NN]
__global__ void scan2_k(int* __restrict__ bsum, int* __restrict__ row_ptr) {
    int lane = threadIdx.x;
    __shared__ int carry;
    if (lane == 0) carry = 0;
    __syncthreads();
    for (int base = 0; base < SCAN_NB; base += 64) {
        int idx = base + lane;
        int v = (idx < SCAN_NB) ? bsum[idx] : 0;
        int s = v;
#pragma unroll
        for (int off = 1; off < 64; off <<= 1) {
            int t = __shfl_up(s, off);
            if (lane >= off) s += t;
        }
        if (idx < SCAN_NB) bsum[idx] = s - v + carry;  // exclusive
        __syncthreads();
        if (lane == 63) carry += s;
        __syncthreads();
    }
    if (lane == 0) row_ptr[NN] = carry;
}

// pass 3: add block base; mirror into cursor
__global__ __launch_bounds__(SCAN_B) void scan3_k(int* __restrict__ row_ptr,
                                                  const int* __restrict__ bsum,
                                                  int* __restrict__ cursor) {
    int i = blockIdx.x * SCAN_B + threadIdx.x;
    if (i < NN) {
        int r = row_ptr[i] + bsum[blockIdx.x];
        row_ptr[i] = r;
        cursor[i] = r;
    }
}

// exclusive scan of bucket histogram -> bucket cursors (single block)
__global__ __launch_bounds__(512) void bscan_k(const int* __restrict__ bhist,
                                               int* __restrict__ bcur) {
    __shared__ int buf[512];
    int tid = threadIdx.x;
    int v = (tid < BUCKETS) ? bhist[tid] : 0;
    buf[tid] = v;
    __syncthreads();
    for (int off = 1; off < 512; off <<= 1) {
        int t = (tid >= off) ? buf[tid - off] : 0;
        __syncthreads();
        buf[tid] += t;
        __syncthreads();
    }
    if (tid < BUCKETS) bcur[tid] = buf[tid] - v;
}

// bucket edges by dst>>8: block-local LDS ranks + per-bucket block reservation
__global__ __launch_bounds__(256) void reorder_k(const int* __restrict__ src,
                                                 const int* __restrict__ dst,
                                                 int* __restrict__ bcur,
                                                 unsigned long long* __restrict__ ebuf) {
    __shared__ int hist[BUCKETS];
    __shared__ int base[BUCKETS];
    int tid = threadIdx.x;
    for (int i = tid; i < BUCKETS; i += 256) hist[i] = 0;
    __syncthreads();
    int e0 = blockIdx.x * (256 * RVPT) + tid;
    unsigned long long pair[RVPT];
    int pr[RVPT];
#pragma unroll
    for (int v = 0; v < RVPT; ++v) {
        int e = e0 + v * 256;
        if (e < NE) {
            int s = src[e], d = dst[e];
            pair[v] = ((unsigned long long)(unsigned)d << 32) | (unsigned)s;
            int b = d >> 8;
            int r = atomicAdd(&hist[b], 1);   // local rank, < 4096
            pr[v] = (b << 12) | r;
        } else pr[v] = -1;
    }
    __syncthreads();
    for (int i = tid; i < BUCKETS; i += 256)
        base[i] = hist[i] ? atomicAdd(&bcur[i], hist[i]) : 0;
    __syncthreads();
#pragma unroll
    for (int v = 0; v < RVPT; ++v) {
        if (pr[v] >= 0) {
            int b = pr[v] >> 12, r = pr[v] & 4095;
            ebuf[(size_t)base[b] + r] = pair[v];
        }
    }
}

// CSR fill from bucketed edges: writes now cluster per 256-node window
__global__ void fill2_k(const unsigned long long* __restrict__ ebuf,
                        int* __restrict__ cursor, int* __restrict__ col) {
    int e = blockIdx.x * blockDim.x + threadIdx.x;
    if (e < NE) {
        unsigned long long p = ebuf[e];
        int d = (int)(p >> 32);
        int s = (int)(p & 0xffffffffu);
        int pos = atomicAdd(&cursor[d], 1);
        col[pos] = s;
    }
}

// ---------------- layer-0 aggregation: x fp32 [N,3] -> magg bf16 [N,3] ----------------
__global__ __launch_bounds__(256) void agg0_k(const int* __restrict__ rp, const int* __restrict__ col,
                                              const float* __restrict__ x, unsigned short* __restrict__ magg) {
    int node = blockIdx.x * 4 + (threadIdx.x >> 6);
    int lane = threadIdx.x & 63;
    int fl = lane & 3, es = lane >> 2;
    int beg = rp[node], end = rp[node + 1];
    float acc = 0.0f;
    for (int e = beg + es; e < end; e += 16) {
        int idx = col[e];
        if (fl < 3) acc += x[(size_t)idx * 3 + fl];
    }
    acc += __shfl(acc, lane + 32);
    acc += __shfl(acc, lane + 16);
    acc += __shfl(acc, lane + 8);
    acc += __shfl(acc, lane + 4);
    if (lane < 3) {
        float inv = 1.0f / fmaxf((float)(end - beg), 1.0f);
        magg[(size_t)node * 3 + lane] = f2bs(acc * inv);
    }
}

// ---------------- generic aggregation: hb bf16 [N,DIN] -> magg bf16 [N,DIN] ----------------
template<int DIN, int FL, int EPW>
__global__ __launch_bounds__(256) void agg_k(const int* __restrict__ rp, const int* __restrict__ col,
                                             const unsigned short* __restrict__ hb,
                                             unsigned short* __restrict__ magg) {
    int node = blockIdx.x * 4 + (threadIdx.x >> 6);
    int lane = threadIdx.x & 63;
    int fl = lane % FL;
    int es = lane / FL;
    int beg = rp[node], end = rp[node + 1];
    float a0 = 0, a1 = 0, a2 = 0, a3 = 0;
    if (es < EPW) {
        for (int e = beg + es; e < end; e += EPW) {
            ushort4 v = *(const ushort4*)(hb + (size_t)col[e] * DIN + fl * 4);
            a0 += bsf(v.x); a1 += bsf(v.y); a2 += bsf(v.z); a3 += bsf(v.w);
        }
    }
    if constexpr (FL == 8) {
        a0 += __shfl(a0, lane + 32); a1 += __shfl(a1, lane + 32); a2 += __shfl(a2, lane + 32); a3 += __shfl(a3, lane + 32);
        a0 += __shfl(a0, lane + 16); a1 += __shfl(a1, lane + 16); a2 += __shfl(a2, lane + 16); a3 += __shfl(a3, lane + 16);
        a0 += __shfl(a0, lane + 8);  a1 += __shfl(a1, lane + 8);  a2 += __shfl(a2, lane + 8);  a3 += __shfl(a3, lane + 8);
    } else if constexpr (FL == 16) {
        a0 += __shfl(a0, lane + 32); a1 += __shfl(a1, lane + 32); a2 += __shfl(a2, lane + 32); a3 += __shfl(a3, lane + 32);
        a0 += __shfl(a0, lane + 16); a1 += __shfl(a1, lane + 16); a2 += __shfl(a2, lane + 16); a3 += __shfl(a3, lane + 16);
    } else { // FL == 24, EPW == 2
        a0 += __shfl(a0, lane + 24); a1 += __shfl(a1, lane + 24); a2 += __shfl(a2, lane + 24); a3 += __shfl(a3, lane + 24);
    }
    if (lane < FL) {
        float inv = 1.0f / fmaxf((float)(end - beg), 1.0f);
        ushort4 o;
        o.x = f2bs(a0 * inv); o.y = f2bs(a1 * inv); o.z = f2bs(a2 * inv); o.w = f2bs(a3 * inv);
        *(ushort4*)(magg + (size_t)node * DIN + lane * 4) = o;
    }
}

// ---------------- tiled update ----------------
template<int DIN, int DOUT, int CT, bool FINAL, bool L0>
__global__ __launch_bounds__(256) void gemm_k(
    const unsigned short* __restrict__ magg, const void* __restrict__ hin,
    const float* __restrict__ Wl, const float* __restrict__ bl, const float* __restrict__ Wr,
    const float* __restrict__ Wf, const float* __restrict__ bfi,
    unsigned short* __restrict__ hout, float* __restrict__ out)
{
    __shared__ float sm[32][DIN + 1];
    __shared__ float sh[32][DIN + 1];
    __shared__ float s4[FINAL ? 32 : 1][FINAL ? 129 : 1];

    int tx = threadIdx.x;
    int base = blockIdx.x * 32;

    if (L0) {
        const float* hx = (const float*)hin;
        for (int f = tx; f < 32 * 3; f += 256) {
            int n = f / 3, k = f - n * 3;
            sm[n][k] = bsf(magg[(size_t)(base + n) * 3 + k]);
            sh[n][k] = hx[(size_t)(base + n) * 3 + k];
        }
    } else {
        const unsigned short* hb = (const unsigned short*)hin;
        constexpr int Q = DIN / 4;
        for (int f = tx; f < 32 * Q; f += 256) {
            int n = f / Q, o = f - n * Q;
            ushort4 vm = *(const ushort4*)(magg + (size_t)(base + n) * DIN + o * 4);
            ushort4 vh = *(const ushort4*)(hb   + (size_t)(base + n) * DIN + o * 4);
            sm[n][o * 4 + 0] = bsf(vm.x); sm[n][o * 4 + 1] = bsf(vm.y);
            sm[n][o * 4 + 2] = bsf(vm.z); sm[n][o * 4 + 3] = bsf(vm.w);
            sh[n][o * 4 + 0] = bsf(vh.x); sh[n][o * 4 + 1] = bsf(vh.y);
            sh[n][o * 4 + 2] = bsf(vh.z); sh[n][o * 4 + 3] = bsf(vh.w);
        }
    }
    __syncthreads();

    int ng = tx >> 5, cg = tx & 31;
    float acc[4][CT];
#pragma unroll
    for (int m = 0; m < 4; ++m)
#pragma unroll
        for (int c = 0; c < CT; ++c) acc[m][c] = bl[cg * CT + c];

#pragma unroll 4
    for (int k = 0; k < (L0 ? 3 : DIN); ++k) {
        float wl[CT], wr[CT];
#pragma unroll
        for (int c = 0; c < CT; ++c) {
            wl[c] = Wl[(size_t)k * DOUT + cg * CT + c];
            wr[c] = Wr[(size_t)k * DOUT + cg * CT + c];
        }
#pragma unroll
        for (int m = 0; m < 4; ++m) {
            float mv = sm[ng * 4 + m][k];
            float hv = sh[ng * 4 + m][k];
#pragma unroll
            for (int c = 0; c < CT; ++c)
                acc[m][c] = fmaf(mv, wl[c], fmaf(hv, wr[c], acc[m][c]));
        }
    }

#pragma unroll
    for (int m = 0; m < 4; ++m)
#pragma unroll
        for (int c = 0; c < CT; ++c) {
            float v = fmaxf(acc[m][c], 0.0f);
            if (!FINAL)
                hout[(size_t)(base + ng * 4 + m) * DOUT + cg * CT + c] = f2bs(v);
            else
                s4[ng * 4 + m][cg * CT + c] = v;
        }

    if (FINAL) {
        __syncthreads();
        if (tx < 128) {
            int n = tx >> 2, c = tx & 3;
            float a = bfi[c];
#pragma unroll 8
            for (int k = 0; k < 128; ++k)
                a = fmaf(s4[n][k], Wf[k * 4 + c], a);
            out[(size_t)(base + n) * 4 + c] = 1.0f / (1.0f + expf(-a));
        }
    }
}

extern "C" void kernel_launch(void* const* d_in, const int* in_sizes, int n_in,
                              void* d_out, int out_size, void* d_ws, size_t ws_size,
                              hipStream_t stream) {
    const float* x   = (const float*)d_in[0];
    const int*   ei  = (const int*)d_in[1];
    const int*   src = ei;
    const int*   dst = ei + NE;
    const float* Wl0 = (const float*)d_in[2];
    const float* bl0 = (const float*)d_in[3];
    const float* Wr0 = (const float*)d_in[4];
    const float* Wl1 = (const float*)d_in[5];
    const float* bl1 = (const float*)d_in[6];
    const float* Wr1 = (const float*)d_in[7];
    const float* Wl2 = (const float*)d_in[8];
    const float* bl2 = (const float*)d_in[9];
    const float* Wr2 = (const float*)d_in[10];
    const float* Wl3 = (const float*)d_in[11];
    const float* bl3 = (const float*)d_in[12];
    const float* Wr3 = (const float*)d_in[13];
    const float* Wf  = (const float*)d_in[14];
    const float* bf  = (const float*)d_in[15];
    float* out = (float*)d_out;

    // ws (ints): row_ptr[NN+2] | cursor[NN] | bsum[128] | bhist[512] | bcur[512] | col[NE]
    // then (bf16): magg[N*96] (unioned with ebuf[NE] u64 = 12.8MB < 19.2MB) | h1 | h2 | h3
    size_t ints = (size_t)(NN + 2) + NN + 128 + 512 + 512 + NE;   // 1,801,154 -> 8B-divisible *4
    size_t need = ints * 4 + (size_t)NN * (96 + 32 + 64 + 96) * 2;
    if (ws_size < need) return;

    int* row_ptr = (int*)d_ws;
    int* cursor  = row_ptr + NN + 2;
    int* bsum    = cursor + NN;
    int* bhist   = bsum + 128;
    int* bcur    = bhist + 512;
    int* col     = bcur + 512;
    unsigned short* magg = (unsigned short*)(col + NE);
    unsigned long long* ebuf = (unsigned long long*)magg;   // union: ebuf dead before magg is born
    unsigned short* h1   = magg + (size_t)NN * 96;
    unsigned short* h2   = h1 + (size_t)NN * 32;
    unsigned short* h3   = h2 + (size_t)NN * 64;

    // CSR build
    hipMemsetAsync(cursor, 0, NN * sizeof(int), stream);
    hipMemsetAsync(bhist, 0, 512 * sizeof(int), stream);
    count_k<<<(NE + 255) / 256, 256, 0, stream>>>(dst, cursor, bhist);
    scan1_k<<<SCAN_NB, SCAN_B, 0, stream>>>(cursor, row_ptr, bsum);
    scan2_k<<<1, 64, 0, stream>>>(bsum, row_ptr);
    scan3_k<<<SCAN_NB, SCAN_B, 0, stream>>>(row_ptr, bsum, cursor);
    bscan_k<<<1, 512, 0, stream>>>(bhist, bcur);
    reorder_k<<<(NE + 256 * RVPT - 1) / (256 * RVPT), 256, 0, stream>>>(src, dst, bcur, ebuf);
    fill2_k<<<(NE + 255) / 256, 256, 0, stream>>>(ebuf, cursor, col);

    const int AGRID = NN / 4;
    const int GGRID = NN / 32;

    // layer 0: x(3) -> h1(32)
    agg0_k<<<AGRID, 256, 0, stream>>>(row_ptr, col, x, magg);
    gemm_k<3, 32, 1, false, true><<<GGRID, 256, 0, stream>>>(
        magg, x, Wl0, bl0, Wr0, nullptr, nullptr, h1, nullptr);

    // layer 1: h1(32) -> h2(64)
    agg_k<32, 8, 8><<<AGRID, 256, 0, stream>>>(row_ptr, col, h1, magg);
    gemm_k<32, 64, 2, false, false><<<GGRID, 256, 0, stream>>>(
        magg, h1, Wl1, bl1, Wr1, nullptr, nullptr, h2, nullptr);

    // layer 2: h2(64) -> h3(96)
    agg_k<64, 16, 4><<<AGRID, 256, 0, stream>>>(row_ptr, col, h2, magg);
    gemm_k<64, 96, 3, false, false><<<GGRID, 256, 0, stream>>>(
        magg, h2, Wl2, bl2, Wr2, nullptr, nullptr, h3, nullptr);

    // layer 3 + final
    agg_k<96, 24, 2><<<AGRID, 256, 0, stream>>>(row_ptr, col, h3, magg);
    gemm_k<96, 128, 4, true, false><<<GGRID, 256, 0, stream>>>(
        magg, h3, Wl3, bl3, Wr3, Wf, bf, nullptr, out);
}

// Round 7
// 475.038 us; speedup vs baseline: 1.4539x; 1.4539x over previous
//
#include <hip/hip_runtime.h>
#include <math.h>

#define NN 100000
#define NE 1600000
#define BUCKETS ((NN + 255) >> 8)              // 391 buckets of 256 nodes
#define RVPT 16                                 // edges per thread in reorder/bhist

__device__ inline float bsf(unsigned short u) { return __uint_as_float(((unsigned)u) << 16); }
__device__ inline unsigned short f2bs(float f) {           // RNE, matches np/hw bf16
    unsigned u = __float_as_uint(f);
    return (unsigned short)((u + 0x7fffu + ((u >> 16) & 1u)) >> 16);
}

// ---------------- CSR build (no scattered global atomics anywhere) ----------------
// bucket histogram, amortized: 4096 edges/block in LDS, then tiny global merge
__global__ __launch_bounds__(256) void bhist_k(const int* __restrict__ dst,
                                               int* __restrict__ bhist) {
    __shared__ int bh[BUCKETS];
    for (int i = threadIdx.x; i < BUCKETS; i += 256) bh[i] = 0;
    __syncthreads();
    int e0 = blockIdx.x * (256 * RVPT) + threadIdx.x;
#pragma unroll
    for (int v = 0; v < RVPT; ++v) {
        int e = e0 + v * 256;
        if (e < NE) atomicAdd(&bh[dst[e] >> 8], 1);
    }
    __syncthreads();
    for (int i = threadIdx.x; i < BUCKETS; i += 256)
        if (bh[i]) atomicAdd(&bhist[i], bh[i]);
}

// exclusive scan of bucket histogram -> bucket cursors (single block)
__global__ __launch_bounds__(512) void bscan_k(const int* __restrict__ bhist,
                                               int* __restrict__ bcur) {
    __shared__ int buf[512];
    int tid = threadIdx.x;
    int v = (tid < BUCKETS) ? bhist[tid] : 0;
    buf[tid] = v;
    __syncthreads();
    for (int off = 1; off < 512; off <<= 1) {
        int t = (tid >= off) ? buf[tid - off] : 0;
        __syncthreads();
        buf[tid] += t;
        __syncthreads();
    }
    if (tid < BUCKETS) bcur[tid] = buf[tid] - v;
}

// bucket edges by dst>>8: block-local LDS ranks + per-bucket block reservation
// after this kernel, bcur[b] == END offset of bucket b (exclusive+count)
__global__ __launch_bounds__(256) void reorder_k(const int* __restrict__ src,
                                                 const int* __restrict__ dst,
                                                 int* __restrict__ bcur,
                                                 unsigned long long* __restrict__ ebuf) {
    __shared__ int hist[BUCKETS];
    __shared__ int base[BUCKETS];
    int tid = threadIdx.x;
    for (int i = tid; i < BUCKETS; i += 256) hist[i] = 0;
    __syncthreads();
    int e0 = blockIdx.x * (256 * RVPT) + tid;
    unsigned long long pair[RVPT];
    int pr[RVPT];
#pragma unroll
    for (int v = 0; v < RVPT; ++v) {
        int e = e0 + v * 256;
        if (e < NE) {
            int s = src[e], d = dst[e];
            pair[v] = ((unsigned long long)(unsigned)d << 32) | (unsigned)s;
            int b = d >> 8;
            int r = atomicAdd(&hist[b], 1);   // local rank, < 4096
            pr[v] = (b << 12) | r;
        } else pr[v] = -1;
    }
    __syncthreads();
    for (int i = tid; i < BUCKETS; i += 256)
        base[i] = hist[i] ? atomicAdd(&bcur[i], hist[i]) : 0;
    __syncthreads();
#pragma unroll
    for (int v = 0; v < RVPT; ++v) {
        if (pr[v] >= 0) {
            int b = pr[v] >> 12, r = pr[v] & 4095;
            ebuf[(size_t)base[b] + r] = pair[v];
        }
    }
}

// per-bucket CSR: LDS histogram -> LDS scan -> row_ptr (coalesced) -> LDS-cursor col fill
// replaces count/scan1/scan2/scan3/fill: zero global atomics, localized col writes
__global__ __launch_bounds__(256) void pcsr_k(const unsigned long long* __restrict__ ebuf,
                                              const int* __restrict__ bend,
                                              int* __restrict__ row_ptr,
                                              int* __restrict__ col) {
    __shared__ int hist[256];
    __shared__ int wsum[4];
    int b = blockIdx.x;
    int tid = threadIdx.x;
    int beg = b ? bend[b - 1] : 0;
    int end = bend[b];

    hist[tid] = 0;
    __syncthreads();
    for (int e = beg + tid; e < end; e += 256)            // coalesced segment read
        atomicAdd(&hist[(int)(ebuf[e] >> 32) & 255], 1);  // LDS atomic, 256-way spread
    __syncthreads();

    int v = hist[tid];
    int lane = tid & 63, wid = tid >> 6;
    int s = v;
#pragma unroll
    for (int off = 1; off < 64; off <<= 1) {
        int t = __shfl_up(s, off);
        if (lane >= off) s += t;
    }
    if (lane == 63) wsum[wid] = s;
    __syncthreads();
    int prev = 0;
#pragma unroll
    for (int w = 0; w < 4; ++w) prev += (w < wid) ? wsum[w] : 0;
    int excl = beg + prev + s - v;                         // global exclusive offset

    int node = b * 256 + tid;
    if (node < NN) row_ptr[node] = excl;
    if (node == NN - 1) row_ptr[NN] = excl + v;            // grand total

    hist[tid] = excl;                                      // reuse as cursor
    __syncthreads();
    for (int e = beg + tid; e < end; e += 256) {
        unsigned long long p = ebuf[e];
        int d = (int)(p >> 32);
        int pos = atomicAdd(&hist[d & 255], 1);
        col[pos] = (int)(p & 0xffffffffu);                 // lands in bucket's ~16KB window
    }
}

// ---------------- layer-0 aggregation: x fp32 [N,3] -> magg bf16 [N,3] ----------------
__global__ __launch_bounds__(256) void agg0_k(const int* __restrict__ rp, const int* __restrict__ col,
                                              const float* __restrict__ x, unsigned short* __restrict__ magg) {
    int node = blockIdx.x * 4 + (threadIdx.x >> 6);
    int lane = threadIdx.x & 63;
    int fl = lane & 3, es = lane >> 2;
    int beg = rp[node], end = rp[node + 1];
    float acc = 0.0f;
    for (int e = beg + es; e < end; e += 16) {
        int idx = col[e];
        if (fl < 3) acc += x[(size_t)idx * 3 + fl];
    }
    acc += __shfl(acc, lane + 32);
    acc += __shfl(acc, lane + 16);
    acc += __shfl(acc, lane + 8);
    acc += __shfl(acc, lane + 4);
    if (lane < 3) {
        float inv = 1.0f / fmaxf((float)(end - beg), 1.0f);
        magg[(size_t)node * 3 + lane] = f2bs(acc * inv);
    }
}

// ---------------- generic aggregation: hb bf16 [N,DIN] -> magg bf16 [N,DIN] ----------------
template<int DIN, int FL, int EPW>
__global__ __launch_bounds__(256) void agg_k(const int* __restrict__ rp, const int* __restrict__ col,
                                             const unsigned short* __restrict__ hb,
                                             unsigned short* __restrict__ magg) {
    int node = blockIdx.x * 4 + (threadIdx.x >> 6);
    int lane = threadIdx.x & 63;
    int fl = lane % FL;
    int es = lane / FL;
    int beg = rp[node], end = rp[node + 1];
    float a0 = 0, a1 = 0, a2 = 0, a3 = 0;
    if (es < EPW) {
        for (int e = beg + es; e < end; e += EPW) {
            ushort4 v = *(const ushort4*)(hb + (size_t)col[e] * DIN + fl * 4);
            a0 += bsf(v.x); a1 += bsf(v.y); a2 += bsf(v.z); a3 += bsf(v.w);
        }
    }
    if constexpr (FL == 8) {
        a0 += __shfl(a0, lane + 32); a1 += __shfl(a1, lane + 32); a2 += __shfl(a2, lane + 32); a3 += __shfl(a3, lane + 32);
        a0 += __shfl(a0, lane + 16); a1 += __shfl(a1, lane + 16); a2 += __shfl(a2, lane + 16); a3 += __shfl(a3, lane + 16);
        a0 += __shfl(a0, lane + 8);  a1 += __shfl(a1, lane + 8);  a2 += __shfl(a2, lane + 8);  a3 += __shfl(a3, lane + 8);
    } else if constexpr (FL == 16) {
        a0 += __shfl(a0, lane + 32); a1 += __shfl(a1, lane + 32); a2 += __shfl(a2, lane + 32); a3 += __shfl(a3, lane + 32);
        a0 += __shfl(a0, lane + 16); a1 += __shfl(a1, lane + 16); a2 += __shfl(a2, lane + 16); a3 += __shfl(a3, lane + 16);
    } else { // FL == 24, EPW == 2
        a0 += __shfl(a0, lane + 24); a1 += __shfl(a1, lane + 24); a2 += __shfl(a2, lane + 24); a3 += __shfl(a3, lane + 24);
    }
    if (lane < FL) {
        float inv = 1.0f / fmaxf((float)(end - beg), 1.0f);
        ushort4 o;
        o.x = f2bs(a0 * inv); o.y = f2bs(a1 * inv); o.z = f2bs(a2 * inv); o.w = f2bs(a3 * inv);
        *(ushort4*)(magg + (size_t)node * DIN + lane * 4) = o;
    }
}

// ---------------- tiled update ----------------
template<int DIN, int DOUT, int CT, bool FINAL, bool L0>
__global__ __launch_bounds__(256) void gemm_k(
    const unsigned short* __restrict__ magg, const void* __restrict__ hin,
    const float* __restrict__ Wl, const float* __restrict__ bl, const float* __restrict__ Wr,
    const float* __restrict__ Wf, const float* __restrict__ bfi,
    unsigned short* __restrict__ hout, float* __restrict__ out)
{
    __shared__ float sm[32][DIN + 1];
    __shared__ float sh[32][DIN + 1];
    __shared__ float s4[FINAL ? 32 : 1][FINAL ? 129 : 1];

    int tx = threadIdx.x;
    int base = blockIdx.x * 32;

    if (L0) {
        const float* hx = (const float*)hin;
        for (int f = tx; f < 32 * 3; f += 256) {
            int n = f / 3, k = f - n * 3;
            sm[n][k] = bsf(magg[(size_t)(base + n) * 3 + k]);
            sh[n][k] = hx[(size_t)(base + n) * 3 + k];
        }
    } else {
        const unsigned short* hb = (const unsigned short*)hin;
        constexpr int Q = DIN / 4;
        for (int f = tx; f < 32 * Q; f += 256) {
            int n = f / Q, o = f - n * Q;
            ushort4 vm = *(const ushort4*)(magg + (size_t)(base + n) * DIN + o * 4);
            ushort4 vh = *(const ushort4*)(hb   + (size_t)(base + n) * DIN + o * 4);
            sm[n][o * 4 + 0] = bsf(vm.x); sm[n][o * 4 + 1] = bsf(vm.y);
            sm[n][o * 4 + 2] = bsf(vm.z); sm[n][o * 4 + 3] = bsf(vm.w);
            sh[n][o * 4 + 0] = bsf(vh.x); sh[n][o * 4 + 1] = bsf(vh.y);
            sh[n][o * 4 + 2] = bsf(vh.z); sh[n][o * 4 + 3] = bsf(vh.w);
        }
    }
    __syncthreads();

    int ng = tx >> 5, cg = tx & 31;
    float acc[4][CT];
#pragma unroll
    for (int m = 0; m < 4; ++m)
#pragma unroll
        for (int c = 0; c < CT; ++c) acc[m][c] = bl[cg * CT + c];

#pragma unroll 4
    for (int k = 0; k < (L0 ? 3 : DIN); ++k) {
        float wl[CT], wr[CT];
#pragma unroll
        for (int c = 0; c < CT; ++c) {
            wl[c] = Wl[(size_t)k * DOUT + cg * CT + c];
            wr[c] = Wr[(size_t)k * DOUT + cg * CT + c];
        }
#pragma unroll
        for (int m = 0; m < 4; ++m) {
            float mv = sm[ng * 4 + m][k];
            float hv = sh[ng * 4 + m][k];
#pragma unroll
            for (int c = 0; c < CT; ++c)
                acc[m][c] = fmaf(mv, wl[c], fmaf(hv, wr[c], acc[m][c]));
        }
    }

#pragma unroll
    for (int m = 0; m < 4; ++m)
#pragma unroll
        for (int c = 0; c < CT; ++c) {
            float v = fmaxf(acc[m][c], 0.0f);
            if (!FINAL)
                hout[(size_t)(base + ng * 4 + m) * DOUT + cg * CT + c] = f2bs(v);
            else
                s4[ng * 4 + m][cg * CT + c] = v;
        }

    if (FINAL) {
        __syncthreads();
        if (tx < 128) {
            int n = tx >> 2, c = tx & 3;
            float a = bfi[c];
#pragma unroll 8
            for (int k = 0; k < 128; ++k)
                a = fmaf(s4[n][k], Wf[k * 4 + c], a);
            out[(size_t)(base + n) * 4 + c] = 1.0f / (1.0f + expf(-a));
        }
    }
}

extern "C" void kernel_launch(void* const* d_in, const int* in_sizes, int n_in,
                              void* d_out, int out_size, void* d_ws, size_t ws_size,
                              hipStream_t stream) {
    const float* x   = (const float*)d_in[0];
    const int*   ei  = (const int*)d_in[1];
    const int*   src = ei;
    const int*   dst = ei + NE;
    const float* Wl0 = (const float*)d_in[2];
    const float* bl0 = (const float*)d_in[3];
    const float* Wr0 = (const float*)d_in[4];
    const float* Wl1 = (const float*)d_in[5];
    const float* bl1 = (const float*)d_in[6];
    const float* Wr1 = (const float*)d_in[7];
    const float* Wl2 = (const float*)d_in[8];
    const float* bl2 = (const float*)d_in[9];
    const float* Wr2 = (const float*)d_in[10];
    const float* Wl3 = (const float*)d_in[11];
    const float* bl3 = (const float*)d_in[12];
    const float* Wr3 = (const float*)d_in[13];
    const float* Wf  = (const float*)d_in[14];
    const float* bf  = (const float*)d_in[15];
    float* out = (float*)d_out;

    // ws (ints): row_ptr[NN+2] | bhist[512] | bcur[512] | col[NE]
    // then (bf16): magg[N*96] (unioned with ebuf[NE] u64 = 12.8MB < 19.2MB) | h1 | h2 | h3
    size_t ints = (size_t)(NN + 2) + 512 + 512 + NE;   // 1,701,026 -> *4 divisible by 8
    size_t need = ints * 4 + (size_t)NN * (96 + 32 + 64 + 96) * 2;
    if (ws_size < need) return;

    int* row_ptr = (int*)d_ws;
    int* bhist   = row_ptr + NN + 2;
    int* bcur    = bhist + 512;
    int* col     = bcur + 512;
    unsigned short* magg = (unsigned short*)(col + NE);
    unsigned long long* ebuf = (unsigned long long*)magg;   // union: ebuf dead before magg is born
    unsigned short* h1   = magg + (size_t)NN * 96;
    unsigned short* h2   = h1 + (size_t)NN * 32;
    unsigned short* h3   = h2 + (size_t)NN * 64;

    // CSR build: bhist -> bscan -> reorder -> per-bucket CSR
    hipMemsetAsync(bhist, 0, 512 * sizeof(int), stream);
    const int EB = (NE + 256 * RVPT - 1) / (256 * RVPT);    // 391
    bhist_k<<<EB, 256, 0, stream>>>(dst, bhist);
    bscan_k<<<1, 512, 0, stream>>>(bhist, bcur);
    reorder_k<<<EB, 256, 0, stream>>>(src, dst, bcur, ebuf);
    pcsr_k<<<BUCKETS, 256, 0, stream>>>(ebuf, bcur, row_ptr, col);

    const int AGRID = NN / 4;
    const int GGRID = NN / 32;

    // layer 0: x(3) -> h1(32)
    agg0_k<<<AGRID, 256, 0, stream>>>(row_ptr, col, x, magg);
    gemm_k<3, 32, 1, false, true><<<GGRID, 256, 0, stream>>>(
        magg, x, Wl0, bl0, Wr0, nullptr, nullptr, h1, nullptr);

    // layer 1: h1(32) -> h2(64)
    agg_k<32, 8, 8><<<AGRID, 256, 0, stream>>>(row_ptr, col, h1, magg);
    gemm_k<32, 64, 2, false, false><<<GGRID, 256, 0, stream>>>(
        magg, h1, Wl1, bl1, Wr1, nullptr, nullptr, h2, nullptr);

    // layer 2: h2(64) -> h3(96)
    agg_k<64, 16, 4><<<AGRID, 256, 0, stream>>>(row_ptr, col, h2, magg);
    gemm_k<64, 96, 3, false, false><<<GGRID, 256, 0, stream>>>(
        magg, h2, Wl2, bl2, Wr2, nullptr, nullptr, h3, nullptr);

    // layer 3 + final
    agg_k<96, 24, 2><<<AGRID, 256, 0, stream>>>(row_ptr, col, h3, magg);
    gemm_k<96, 128, 4, true, false><<<GGRID, 256, 0, stream>>>(
        magg, h3, Wl3, bl3, Wr3, Wf, bf, nullptr, out);
}

// Round 8
// 359.636 us; speedup vs baseline: 1.9205x; 1.3209x over previous
//
#include <hip/hip_runtime.h>
#include <math.h>

#define NN 100000
#define NE 1600000
#define BUCKETS ((NN + 255) >> 8)              // 391 buckets of 256 nodes
#define RVPT 16                                 // edges per thread in reorder/bhist

typedef short bf16x8 __attribute__((ext_vector_type(8)));
typedef float f32x4 __attribute__((ext_vector_type(4)));

__device__ inline float bsf(unsigned short u) { return __uint_as_float(((unsigned)u) << 16); }
__device__ inline unsigned short f2bs(float f) {           // RNE, matches np/hw bf16
    unsigned u = __float_as_uint(f);
    return (unsigned short)((u + 0x7fffu + ((u >> 16) & 1u)) >> 16);
}

// ---------------- CSR build (no scattered global atomics) ----------------
__global__ __launch_bounds__(256) void bhist_k(const int* __restrict__ dst,
                                               int* __restrict__ bhist) {
    __shared__ int bh[BUCKETS];
    for (int i = threadIdx.x; i < BUCKETS; i += 256) bh[i] = 0;
    __syncthreads();
    int e0 = blockIdx.x * (256 * RVPT) + threadIdx.x;
#pragma unroll
    for (int v = 0; v < RVPT; ++v) {
        int e = e0 + v * 256;
        if (e < NE) atomicAdd(&bh[dst[e] >> 8], 1);
    }
    __syncthreads();
    for (int i = threadIdx.x; i < BUCKETS; i += 256)
        if (bh[i]) atomicAdd(&bhist[i], bh[i]);
}

__global__ __launch_bounds__(512) void bscan_k(const int* __restrict__ bhist,
                                               int* __restrict__ bcur) {
    __shared__ int buf[512];
    int tid = threadIdx.x;
    int v = (tid < BUCKETS) ? bhist[tid] : 0;
    buf[tid] = v;
    __syncthreads();
    for (int off = 1; off < 512; off <<= 1) {
        int t = (tid >= off) ? buf[tid - off] : 0;
        __syncthreads();
        buf[tid] += t;
        __syncthreads();
    }
    if (tid < BUCKETS) bcur[tid] = buf[tid] - v;
}

__global__ __launch_bounds__(256) void reorder_k(const int* __restrict__ src,
                                                 const int* __restrict__ dst,
                                                 int* __restrict__ bcur,
                                                 unsigned long long* __restrict__ ebuf) {
    __shared__ int hist[BUCKETS];
    __shared__ int base[BUCKETS];
    int tid = threadIdx.x;
    for (int i = tid; i < BUCKETS; i += 256) hist[i] = 0;
    __syncthreads();
    int e0 = blockIdx.x * (256 * RVPT) + tid;
    unsigned long long pair[RVPT];
    int pr[RVPT];
#pragma unroll
    for (int v = 0; v < RVPT; ++v) {
        int e = e0 + v * 256;
        if (e < NE) {
            int s = src[e], d = dst[e];
            pair[v] = ((unsigned long long)(unsigned)d << 32) | (unsigned)s;
            int b = d >> 8;
            int r = atomicAdd(&hist[b], 1);
            pr[v] = (b << 12) | r;
        } else pr[v] = -1;
    }
    __syncthreads();
    for (int i = tid; i < BUCKETS; i += 256)
        base[i] = hist[i] ? atomicAdd(&bcur[i], hist[i]) : 0;
    __syncthreads();
#pragma unroll
    for (int v = 0; v < RVPT; ++v) {
        if (pr[v] >= 0) {
            int b = pr[v] >> 12, r = pr[v] & 4095;
            ebuf[(size_t)base[b] + r] = pair[v];
        }
    }
}

__global__ __launch_bounds__(256) void pcsr_k(const unsigned long long* __restrict__ ebuf,
                                              const int* __restrict__ bend,
                                              int* __restrict__ row_ptr,
                                              int* __restrict__ col) {
    __shared__ int hist[256];
    __shared__ int wsum[4];
    int b = blockIdx.x;
    int tid = threadIdx.x;
    int beg = b ? bend[b - 1] : 0;
    int end = bend[b];

    hist[tid] = 0;
    __syncthreads();
    for (int e = beg + tid; e < end; e += 256)
        atomicAdd(&hist[(int)(ebuf[e] >> 32) & 255], 1);
    __syncthreads();

    int v = hist[tid];
    int lane = tid & 63, wid = tid >> 6;
    int s = v;
#pragma unroll
    for (int off = 1; off < 64; off <<= 1) {
        int t = __shfl_up(s, off);
        if (lane >= off) s += t;
    }
    if (lane == 63) wsum[wid] = s;
    __syncthreads();
    int prev = 0;
#pragma unroll
    for (int w = 0; w < 4; ++w) prev += (w < wid) ? wsum[w] : 0;
    int excl = beg + prev + s - v;

    int node = b * 256 + tid;
    if (node < NN) row_ptr[node] = excl;
    if (node == NN - 1) row_ptr[NN] = excl + v;

    hist[tid] = excl;
    __syncthreads();
    for (int e = beg + tid; e < end; e += 256) {
        unsigned long long p = ebuf[e];
        int d = (int)(p >> 32);
        int pos = atomicAdd(&hist[d & 255], 1);
        col[pos] = (int)(p & 0xffffffffu);
    }
}

// ---------------- weight convert: [Wl;Wr] fp32 -> Wt bf16 [DOUT][2*DIN] ----------------
template<int DIN, int DOUT>
__global__ void wcvt_k(const float* __restrict__ Wl, const float* __restrict__ Wr,
                       unsigned short* __restrict__ Wt) {
    int idx = blockIdx.x * 256 + threadIdx.x;
    if (idx < DOUT * 2 * DIN) {
        int j = idx / (2 * DIN), k = idx - j * 2 * DIN;
        float v = (k < DIN) ? Wl[(size_t)k * DOUT + j] : Wr[(size_t)(k - DIN) * DOUT + j];
        Wt[idx] = f2bs(v);
    }
}

// ---------------- layer-0 aggregation ----------------
__global__ __launch_bounds__(256) void agg0_k(const int* __restrict__ rp, const int* __restrict__ col,
                                              const float* __restrict__ x, unsigned short* __restrict__ magg) {
    int node = blockIdx.x * 4 + (threadIdx.x >> 6);
    int lane = threadIdx.x & 63;
    int fl = lane & 3, es = lane >> 2;
    int beg = rp[node], end = rp[node + 1];
    float acc = 0.0f;
    for (int e = beg + es; e < end; e += 16) {
        int idx = col[e];
        if (fl < 3) acc += x[(size_t)idx * 3 + fl];
    }
    acc += __shfl(acc, lane + 32);
    acc += __shfl(acc, lane + 16);
    acc += __shfl(acc, lane + 8);
    acc += __shfl(acc, lane + 4);
    if (lane < 3) {
        float inv = 1.0f / fmaxf((float)(end - beg), 1.0f);
        magg[(size_t)node * 3 + lane] = f2bs(acc * inv);
    }
}

// ---------------- generic aggregation ----------------
template<int DIN, int FL, int EPW>
__global__ __launch_bounds__(256) void agg_k(const int* __restrict__ rp, const int* __restrict__ col,
                                             const unsigned short* __restrict__ hb,
                                             unsigned short* __restrict__ magg) {
    int node = blockIdx.x * 4 + (threadIdx.x >> 6);
    int lane = threadIdx.x & 63;
    int fl = lane % FL;
    int es = lane / FL;
    int beg = rp[node], end = rp[node + 1];
    float a0 = 0, a1 = 0, a2 = 0, a3 = 0;
    if (es < EPW) {
        for (int e = beg + es; e < end; e += EPW) {
            ushort4 v = *(const ushort4*)(hb + (size_t)col[e] * DIN + fl * 4);
            a0 += bsf(v.x); a1 += bsf(v.y); a2 += bsf(v.z); a3 += bsf(v.w);
        }
    }
    if constexpr (FL == 8) {
        a0 += __shfl(a0, lane + 32); a1 += __shfl(a1, lane + 32); a2 += __shfl(a2, lane + 32); a3 += __shfl(a3, lane + 32);
        a0 += __shfl(a0, lane + 16); a1 += __shfl(a1, lane + 16); a2 += __shfl(a2, lane + 16); a3 += __shfl(a3, lane + 16);
        a0 += __shfl(a0, lane + 8);  a1 += __shfl(a1, lane + 8);  a2 += __shfl(a2, lane + 8);  a3 += __shfl(a3, lane + 8);
    } else if constexpr (FL == 16) {
        a0 += __shfl(a0, lane + 32); a1 += __shfl(a1, lane + 32); a2 += __shfl(a2, lane + 32); a3 += __shfl(a3, lane + 32);
        a0 += __shfl(a0, lane + 16); a1 += __shfl(a1, lane + 16); a2 += __shfl(a2, lane + 16); a3 += __shfl(a3, lane + 16);
    } else { // FL == 24, EPW == 2
        a0 += __shfl(a0, lane + 24); a1 += __shfl(a1, lane + 24); a2 += __shfl(a2, lane + 24); a3 += __shfl(a3, lane + 24);
    }
    if (lane < FL) {
        float inv = 1.0f / fmaxf((float)(end - beg), 1.0f);
        ushort4 o;
        o.x = f2bs(a0 * inv); o.y = f2bs(a1 * inv); o.z = f2bs(a2 * inv); o.w = f2bs(a3 * inv);
        *(ushort4*)(magg + (size_t)node * DIN + lane * 4) = o;
    }
}

// ---------------- scalar update (layer 0 only, K=6) ----------------
template<int DIN, int DOUT, int CT, bool FINAL, bool L0>
__global__ __launch_bounds__(256) void gemm_k(
    const unsigned short* __restrict__ magg, const void* __restrict__ hin,
    const float* __restrict__ Wl, const float* __restrict__ bl, const float* __restrict__ Wr,
    const float* __restrict__ Wf, const float* __restrict__ bfi,
    unsigned short* __restrict__ hout, float* __restrict__ out)
{
    __shared__ float sm[32][DIN + 1];
    __shared__ float sh[32][DIN + 1];

    int tx = threadIdx.x;
    int base = blockIdx.x * 32;

    const float* hx = (const float*)hin;
    for (int f = tx; f < 32 * 3; f += 256) {
        int n = f / 3, k = f - n * 3;
        sm[n][k] = bsf(magg[(size_t)(base + n) * 3 + k]);
        sh[n][k] = hx[(size_t)(base + n) * 3 + k];
    }
    __syncthreads();

    int ng = tx >> 5, cg = tx & 31;
    float acc[4][CT];
#pragma unroll
    for (int m = 0; m < 4; ++m)
#pragma unroll
        for (int c = 0; c < CT; ++c) acc[m][c] = bl[cg * CT + c];

#pragma unroll
    for (int k = 0; k < 3; ++k) {
        float wl[CT], wr[CT];
#pragma unroll
        for (int c = 0; c < CT; ++c) {
            wl[c] = Wl[(size_t)k * DOUT + cg * CT + c];
            wr[c] = Wr[(size_t)k * DOUT + cg * CT + c];
        }
#pragma unroll
        for (int m = 0; m < 4; ++m) {
            float mv = sm[ng * 4 + m][k];
            float hv = sh[ng * 4 + m][k];
#pragma unroll
            for (int c = 0; c < CT; ++c)
                acc[m][c] = fmaf(mv, wl[c], fmaf(hv, wr[c], acc[m][c]));
        }
    }

#pragma unroll
    for (int m = 0; m < 4; ++m)
#pragma unroll
        for (int c = 0; c < CT; ++c) {
            float v = fmaxf(acc[m][c], 0.0f);
            hout[(size_t)(base + ng * 4 + m) * DOUT + cg * CT + c] = f2bs(v);
        }
}

// ---------------- MFMA update: relu([magg|h] @ Wt^T + bl), optional fused final ----------------
// block = 256 thr = 4 waves, 64 nodes; wave -> 16 nodes x DOUT
template<int DIN, int DOUT, bool FINAL>
__global__ __launch_bounds__(256) void mgemm_k(
    const unsigned short* __restrict__ magg, const unsigned short* __restrict__ h,
    const unsigned short* __restrict__ Wt, const float* __restrict__ bl,
    const float* __restrict__ Wf, const float* __restrict__ bfi,
    unsigned short* __restrict__ hout, float* __restrict__ out)
{
    constexpr int K2  = 2 * DIN;
    constexpr int STR = K2 + 8;           // padded row stride (ushorts): +16B kills conflicts
    constexpr int NT  = DOUT / 16;        // N tiles per wave
    constexpr int KS  = K2 / 32;          // K steps
    __shared__ unsigned short lA[64 * STR];
    __shared__ unsigned short lB[DOUT * STR];

    int tx = threadIdx.x;
    int base = blockIdx.x * 64;

    // stage A: [64][K2] = [magg | h], 16B vector loads, zero-fill past NN
    constexpr int CPM = DIN / 8;
    for (int c = tx; c < 64 * CPM; c += 256) {
        int n = c / CPM, o = (c - n * CPM) * 8;
        int node = base + n;
        uint4 vm = make_uint4(0, 0, 0, 0), vh = vm;
        if (node < NN) {
            vm = *(const uint4*)(magg + (size_t)node * DIN + o);
            vh = *(const uint4*)(h    + (size_t)node * DIN + o);
        }
        *(uint4*)(lA + n * STR + o)       = vm;
        *(uint4*)(lA + n * STR + DIN + o) = vh;
    }
    // stage B: Wt[DOUT][K2]
    constexpr int CPW = K2 / 8;
    for (int c = tx; c < DOUT * CPW; c += 256) {
        int j = c / CPW, o = (c - j * CPW) * 8;
        *(uint4*)(lB + j * STR + o) = *(const uint4*)(Wt + (size_t)j * K2 + o);
    }
    __syncthreads();

    int lane = tx & 63;
    int wm = tx >> 6;                     // wave id = M-tile
    int r16 = lane & 15, kg = lane >> 4;  // row/col in tile; k-group

    f32x4 acc[NT];
#pragma unroll
    for (int t = 0; t < NT; ++t) acc[t] = (f32x4){0.0f, 0.0f, 0.0f, 0.0f};

#pragma unroll
    for (int kk = 0; kk < KS; ++kk) {
        bf16x8 a = *(const bf16x8*)(lA + (wm * 16 + r16) * STR + kk * 32 + kg * 8);
#pragma unroll
        for (int t = 0; t < NT; ++t) {
            bf16x8 b = *(const bf16x8*)(lB + (t * 16 + r16) * STR + kk * 32 + kg * 8);
            acc[t] = __builtin_amdgcn_mfma_f32_16x16x32_bf16(a, b, acc[t], 0, 0, 0);
        }
    }

    if (!FINAL) {
#pragma unroll
        for (int t = 0; t < NT; ++t)
#pragma unroll
            for (int r = 0; r < 4; ++r) {
                int node = base + wm * 16 + kg * 4 + r;       // C/D: row=(lane>>4)*4+reg
                int colj = t * 16 + r16;                       //      col=lane&15
                float v = fmaxf(acc[t][r] + bl[colj], 0.0f);
                if (node < NN) hout[(size_t)node * DOUT + colj] = f2bs(v);
            }
    } else {
        __syncthreads();                   // all waves done reading lB -> reuse as f32 tile
        float* s4 = (float*)lB;            // [64][129]
#pragma unroll
        for (int t = 0; t < NT; ++t)
#pragma unroll
            for (int r = 0; r < 4; ++r) {
                int nl = wm * 16 + kg * 4 + r;
                int colj = t * 16 + r16;
                s4[nl * 129 + colj] = fmaxf(acc[t][r] + bl[colj], 0.0f);
            }
        __syncthreads();
        int nl = tx >> 2, c = tx & 3;
        int node = base + nl;
        if (node < NN) {
            float a = bfi[c];
#pragma unroll 8
            for (int k = 0; k < 128; ++k)
                a = fmaf(s4[nl * 129 + k], Wf[k * 4 + c], a);
            out[(size_t)node * 4 + c] = 1.0f / (1.0f + expf(-a));
        }
    }
}

extern "C" void kernel_launch(void* const* d_in, const int* in_sizes, int n_in,
                              void* d_out, int out_size, void* d_ws, size_t ws_size,
                              hipStream_t stream) {
    const float* x   = (const float*)d_in[0];
    const int*   ei  = (const int*)d_in[1];
    const int*   src = ei;
    const int*   dst = ei + NE;
    const float* Wl0 = (const float*)d_in[2];
    const float* bl0 = (const float*)d_in[3];
    const float* Wr0 = (const float*)d_in[4];
    const float* Wl1 = (const float*)d_in[5];
    const float* bl1 = (const float*)d_in[6];
    const float* Wr1 = (const float*)d_in[7];
    const float* Wl2 = (const float*)d_in[8];
    const float* bl2 = (const float*)d_in[9];
    const float* Wr2 = (const float*)d_in[10];
    const float* Wl3 = (const float*)d_in[11];
    const float* bl3 = (const float*)d_in[12];
    const float* Wr3 = (const float*)d_in[13];
    const float* Wf  = (const float*)d_in[14];
    const float* bf  = (const float*)d_in[15];
    float* out = (float*)d_out;

    // ws (ints): row_ptr[NN+2] | bhist[512] | bcur[512] | col[NE] | pad[2]
    // then bf16: magg[N*96] (union ebuf u64) | h1[N*32] | h2[N*64] | h3[N*96] | Wt1 | Wt2 | Wt3
    size_t ints = (size_t)(NN + 2) + 512 + 512 + NE + 2;     // *4 => 16B-aligned end
    size_t need = ints * 4 + (size_t)NN * (96 + 32 + 64 + 96) * 2
                + (size_t)(64 * 64 + 96 * 128 + 128 * 192) * 2;
    if (ws_size < need) return;

    int* row_ptr = (int*)d_ws;
    int* bhist   = row_ptr + NN + 2;
    int* bcur    = bhist + 512;
    int* col     = bcur + 512;
    unsigned short* magg = (unsigned short*)(col + NE + 2);
    unsigned long long* ebuf = (unsigned long long*)magg;    // dead before magg is born
    unsigned short* h1   = magg + (size_t)NN * 96;
    unsigned short* h2   = h1 + (size_t)NN * 32;
    unsigned short* h3   = h2 + (size_t)NN * 64;
    unsigned short* wt1  = h3 + (size_t)NN * 96;
    unsigned short* wt2  = wt1 + 64 * 64;
    unsigned short* wt3  = wt2 + 96 * 128;

    // weight conversion (independent of CSR)
    wcvt_k<32, 64><<<(64 * 64 + 255) / 256, 256, 0, stream>>>(Wl1, Wr1, wt1);
    wcvt_k<64, 96><<<(96 * 128 + 255) / 256, 256, 0, stream>>>(Wl2, Wr2, wt2);
    wcvt_k<96, 128><<<(128 * 192 + 255) / 256, 256, 0, stream>>>(Wl3, Wr3, wt3);

    // CSR build
    hipMemsetAsync(bhist, 0, 512 * sizeof(int), stream);
    const int EB = (NE + 256 * RVPT - 1) / (256 * RVPT);
    bhist_k<<<EB, 256, 0, stream>>>(dst, bhist);
    bscan_k<<<1, 512, 0, stream>>>(bhist, bcur);
    reorder_k<<<EB, 256, 0, stream>>>(src, dst, bcur, ebuf);
    pcsr_k<<<BUCKETS, 256, 0, stream>>>(ebuf, bcur, row_ptr, col);

    const int AGRID = NN / 4;
    const int MG    = (NN + 63) / 64;    // 1563

    // layer 0: x(3) -> h1(32)  (scalar, K=6)
    agg0_k<<<AGRID, 256, 0, stream>>>(row_ptr, col, x, magg);
    gemm_k<3, 32, 1, false, true><<<NN / 32, 256, 0, stream>>>(
        magg, x, Wl0, bl0, Wr0, nullptr, nullptr, h1, nullptr);

    // layer 1: h1(32) -> h2(64)
    agg_k<32, 8, 8><<<AGRID, 256, 0, stream>>>(row_ptr, col, h1, magg);
    mgemm_k<32, 64, false><<<MG, 256, 0, stream>>>(
        magg, h1, wt1, bl1, nullptr, nullptr, h2, nullptr);

    // layer 2: h2(64) -> h3(96)
    agg_k<64, 16, 4><<<AGRID, 256, 0, stream>>>(row_ptr, col, h2, magg);
    mgemm_k<64, 96, false><<<MG, 256, 0, stream>>>(
        magg, h2, wt2, bl2, nullptr, nullptr, h3, nullptr);

    // layer 3 + final: h3(96) -> [128] -> out(4)
    agg_k<96, 24, 2><<<AGRID, 256, 0, stream>>>(row_ptr, col, h3, magg);
    mgemm_k<96, 128, true><<<MG, 256, 0, stream>>>(
        magg, h3, wt3, bl3, Wf, bf, nullptr, out);
}

// Round 9
// 305.271 us; speedup vs baseline: 2.2625x; 1.1781x over previous
//
#include <hip/hip_runtime.h>
#include <math.h>

#define NN 100000
#define NE 1600000
#define BUCKETS ((NN + 255) >> 8)              // 391 buckets of 256 nodes
#define RVPT 16                                 // edges per thread in reorder/bhist

typedef short bf16x8 __attribute__((ext_vector_type(8)));
typedef float f32x4 __attribute__((ext_vector_type(4)));

__device__ inline float bsf(unsigned short u) { return __uint_as_float(((unsigned)u) << 16); }
__device__ inline unsigned short f2bs(float f) {           // RNE, matches np/hw bf16
    unsigned u = __float_as_uint(f);
    return (unsigned short)((u + 0x7fffu + ((u >> 16) & 1u)) >> 16);
}

// ---------------- CSR build (no scattered global atomics) ----------------
__global__ __launch_bounds__(256) void bhist_k(const int* __restrict__ dst,
                                               int* __restrict__ bhist) {
    __shared__ int bh[BUCKETS];
    for (int i = threadIdx.x; i < BUCKETS; i += 256) bh[i] = 0;
    __syncthreads();
    int e0 = blockIdx.x * (256 * RVPT) + threadIdx.x;
#pragma unroll
    for (int v = 0; v < RVPT; ++v) {
        int e = e0 + v * 256;
        if (e < NE) atomicAdd(&bh[dst[e] >> 8], 1);
    }
    __syncthreads();
    for (int i = threadIdx.x; i < BUCKETS; i += 256)
        if (bh[i]) atomicAdd(&bhist[i], bh[i]);
}

__global__ __launch_bounds__(512) void bscan_k(const int* __restrict__ bhist,
                                               int* __restrict__ bcur) {
    __shared__ int buf[512];
    int tid = threadIdx.x;
    int v = (tid < BUCKETS) ? bhist[tid] : 0;
    buf[tid] = v;
    __syncthreads();
    for (int off = 1; off < 512; off <<= 1) {
        int t = (tid >= off) ? buf[tid - off] : 0;
        __syncthreads();
        buf[tid] += t;
        __syncthreads();
    }
    if (tid < BUCKETS) bcur[tid] = buf[tid] - v;
}

__global__ __launch_bounds__(256) void reorder_k(const int* __restrict__ src,
                                                 const int* __restrict__ dst,
                                                 int* __restrict__ bcur,
                                                 unsigned long long* __restrict__ ebuf) {
    __shared__ int hist[BUCKETS];
    __shared__ int base[BUCKETS];
    int tid = threadIdx.x;
    for (int i = tid; i < BUCKETS; i += 256) hist[i] = 0;
    __syncthreads();
    int e0 = blockIdx.x * (256 * RVPT) + tid;
    unsigned long long pair[RVPT];
    int pr[RVPT];
#pragma unroll
    for (int v = 0; v < RVPT; ++v) {
        int e = e0 + v * 256;
        if (e < NE) {
            int s = src[e], d = dst[e];
            pair[v] = ((unsigned long long)(unsigned)d << 32) | (unsigned)s;
            int b = d >> 8;
            int r = atomicAdd(&hist[b], 1);
            pr[v] = (b << 12) | r;
        } else pr[v] = -1;
    }
    __syncthreads();
    for (int i = tid; i < BUCKETS; i += 256)
        base[i] = hist[i] ? atomicAdd(&bcur[i], hist[i]) : 0;
    __syncthreads();
#pragma unroll
    for (int v = 0; v < RVPT; ++v) {
        if (pr[v] >= 0) {
            int b = pr[v] >> 12, r = pr[v] & 4095;
            ebuf[(size_t)base[b] + r] = pair[v];
        }
    }
}

__global__ __launch_bounds__(256) void pcsr_k(const unsigned long long* __restrict__ ebuf,
                                              const int* __restrict__ bend,
                                              int* __restrict__ row_ptr,
                                              int* __restrict__ col) {
    __shared__ int hist[256];
    __shared__ int wsum[4];
    int b = blockIdx.x;
    int tid = threadIdx.x;
    int beg = b ? bend[b - 1] : 0;
    int end = bend[b];

    hist[tid] = 0;
    __syncthreads();
    for (int e = beg + tid; e < end; e += 256)
        atomicAdd(&hist[(int)(ebuf[e] >> 32) & 255], 1);
    __syncthreads();

    int v = hist[tid];
    int lane = tid & 63, wid = tid >> 6;
    int s = v;
#pragma unroll
    for (int off = 1; off < 64; off <<= 1) {
        int t = __shfl_up(s, off);
        if (lane >= off) s += t;
    }
    if (lane == 63) wsum[wid] = s;
    __syncthreads();
    int prev = 0;
#pragma unroll
    for (int w = 0; w < 4; ++w) prev += (w < wid) ? wsum[w] : 0;
    int excl = beg + prev + s - v;

    int node = b * 256 + tid;
    if (node < NN) row_ptr[node] = excl;
    if (node == NN - 1) row_ptr[NN] = excl + v;

    hist[tid] = excl;
    __syncthreads();
    for (int e = beg + tid; e < end; e += 256) {
        unsigned long long p = ebuf[e];
        int d = (int)(p >> 32);
        int pos = atomicAdd(&hist[d & 255], 1);
        col[pos] = (int)(p & 0xffffffffu);
    }
}

// ---------------- weight convert: [Wl;Wr] fp32 -> Wt bf16 [DOUT][2*DIN] ----------------
template<int DIN, int DOUT>
__global__ void wcvt_k(const float* __restrict__ Wl, const float* __restrict__ Wr,
                       unsigned short* __restrict__ Wt) {
    int idx = blockIdx.x * 256 + threadIdx.x;
    if (idx < DOUT * 2 * DIN) {
        int j = idx / (2 * DIN), k = idx - j * 2 * DIN;
        float v = (k < DIN) ? Wl[(size_t)k * DOUT + j] : Wr[(size_t)(k - DIN) * DOUT + j];
        Wt[idx] = f2bs(v);
    }
}

// ---------------- layer-0 aggregation ----------------
__global__ __launch_bounds__(256) void agg0_k(const int* __restrict__ rp, const int* __restrict__ col,
                                              const float* __restrict__ x, unsigned short* __restrict__ magg) {
    int node = blockIdx.x * 4 + (threadIdx.x >> 6);
    int lane = threadIdx.x & 63;
    int fl = lane & 3, es = lane >> 2;
    int beg = rp[node], end = rp[node + 1];
    float acc = 0.0f;
    for (int e = beg + es; e < end; e += 16) {
        int idx = col[e];
        if (fl < 3) acc += x[(size_t)idx * 3 + fl];
    }
    acc += __shfl(acc, lane + 32);
    acc += __shfl(acc, lane + 16);
    acc += __shfl(acc, lane + 8);
    acc += __shfl(acc, lane + 4);
    if (lane < 3) {
        float inv = 1.0f / fmaxf((float)(end - beg), 1.0f);
        magg[(size_t)node * 3 + lane] = f2bs(acc * inv);
    }
}

// ---------------- generic aggregation: hb bf16 [N,DIN] -> magg bf16 [N,DIN] ----------------
// wave per node. FL lanes x 16B (uint4 = 8 bf16) cover a row; EPW edge slots in flight.
// 2x-unrolled edge loop -> up to 2*EPW outstanding row reads per wave.
template<int DIN, int FL, int EPW>
__global__ __launch_bounds__(256) void agg_k(const int* __restrict__ rp, const int* __restrict__ col,
                                             const unsigned short* __restrict__ hb,
                                             unsigned short* __restrict__ magg) {
    int node = blockIdx.x * 4 + (threadIdx.x >> 6);
    int lane = threadIdx.x & 63;
    int fl = lane % FL;
    int es = lane / FL;
    int beg = rp[node], end = rp[node + 1];

    float a[8];
#pragma unroll
    for (int i = 0; i < 8; ++i) a[i] = 0.0f;

    if (es < EPW) {
        int e = beg + es;
        for (; e + EPW < end; e += 2 * EPW) {
            uint4 v0 = *(const uint4*)(hb + (size_t)col[e]       * DIN + fl * 8);
            uint4 v1 = *(const uint4*)(hb + (size_t)col[e + EPW] * DIN + fl * 8);
            const unsigned short* p0 = (const unsigned short*)&v0;
            const unsigned short* p1 = (const unsigned short*)&v1;
#pragma unroll
            for (int i = 0; i < 8; ++i) a[i] += bsf(p0[i]) + bsf(p1[i]);
        }
        if (e < end) {
            uint4 v0 = *(const uint4*)(hb + (size_t)col[e] * DIN + fl * 8);
            const unsigned short* p0 = (const unsigned short*)&v0;
#pragma unroll
            for (int i = 0; i < 8; ++i) a[i] += bsf(p0[i]);
        }
    }

    // reduce across EPW groups (stride FL); __shfl reads pre-step values (parallel semantics)
    if constexpr (FL == 4) {        // EPW=16: +4,+8,+16,+32
#pragma unroll
        for (int i = 0; i < 8; ++i) {
            a[i] += __shfl(a[i], lane + 4);
            a[i] += __shfl(a[i], lane + 8);
            a[i] += __shfl(a[i], lane + 16);
            a[i] += __shfl(a[i], lane + 32);
        }
    } else if constexpr (FL == 8) { // EPW=8: +8,+16,+32
#pragma unroll
        for (int i = 0; i < 8; ++i) {
            a[i] += __shfl(a[i], lane + 8);
            a[i] += __shfl(a[i], lane + 16);
            a[i] += __shfl(a[i], lane + 32);
        }
    } else {                        // FL==12, EPW=5: capture g4 first (lanes 60-63 are zero)
#pragma unroll
        for (int i = 0; i < 8; ++i) {
            float g4 = __shfl(a[i], lane + 48);
            a[i] += __shfl(a[i], lane + 12);
            a[i] += __shfl(a[i], lane + 24);
            a[i] += g4;
        }
    }

    if (lane < FL) {
        float inv = 1.0f / fmaxf((float)(end - beg), 1.0f);
        unsigned short o[8];
#pragma unroll
        for (int i = 0; i < 8; ++i) o[i] = f2bs(a[i] * inv);
        *(uint4*)(magg + (size_t)node * DIN + fl * 8) = *(const uint4*)o;
    }
}

// ---------------- scalar update (layer 0 only, K=6) ----------------
template<int DIN, int DOUT, int CT, bool FINAL, bool L0>
__global__ __launch_bounds__(256) void gemm_k(
    const unsigned short* __restrict__ magg, const void* __restrict__ hin,
    const float* __restrict__ Wl, const float* __restrict__ bl, const float* __restrict__ Wr,
    const float* __restrict__ Wf, const float* __restrict__ bfi,
    unsigned short* __restrict__ hout, float* __restrict__ out)
{
    __shared__ float sm[32][DIN + 1];
    __shared__ float sh[32][DIN + 1];

    int tx = threadIdx.x;
    int base = blockIdx.x * 32;

    const float* hx = (const float*)hin;
    for (int f = tx; f < 32 * 3; f += 256) {
        int n = f / 3, k = f - n * 3;
        sm[n][k] = bsf(magg[(size_t)(base + n) * 3 + k]);
        sh[n][k] = hx[(size_t)(base + n) * 3 + k];
    }
    __syncthreads();

    int ng = tx >> 5, cg = tx & 31;
    float acc[4][CT];
#pragma unroll
    for (int m = 0; m < 4; ++m)
#pragma unroll
        for (int c = 0; c < CT; ++c) acc[m][c] = bl[cg * CT + c];

#pragma unroll
    for (int k = 0; k < 3; ++k) {
        float wl[CT], wr[CT];
#pragma unroll
        for (int c = 0; c < CT; ++c) {
            wl[c] = Wl[(size_t)k * DOUT + cg * CT + c];
            wr[c] = Wr[(size_t)k * DOUT + cg * CT + c];
        }
#pragma unroll
        for (int m = 0; m < 4; ++m) {
            float mv = sm[ng * 4 + m][k];
            float hv = sh[ng * 4 + m][k];
#pragma unroll
            for (int c = 0; c < CT; ++c)
                acc[m][c] = fmaf(mv, wl[c], fmaf(hv, wr[c], acc[m][c]));
        }
    }

#pragma unroll
    for (int m = 0; m < 4; ++m)
#pragma unroll
        for (int c = 0; c < CT; ++c) {
            float v = fmaxf(acc[m][c], 0.0f);
            hout[(size_t)(base + ng * 4 + m) * DOUT + cg * CT + c] = f2bs(v);
        }
}

// ---------------- MFMA update: relu([magg|h] @ Wt^T + bl), optional fused final ----------------
template<int DIN, int DOUT, bool FINAL>
__global__ __launch_bounds__(256) void mgemm_k(
    const unsigned short* __restrict__ magg, const unsigned short* __restrict__ h,
    const unsigned short* __restrict__ Wt, const float* __restrict__ bl,
    const float* __restrict__ Wf, const float* __restrict__ bfi,
    unsigned short* __restrict__ hout, float* __restrict__ out)
{
    constexpr int K2  = 2 * DIN;
    constexpr int STR = K2 + 8;
    constexpr int NT  = DOUT / 16;
    constexpr int KS  = K2 / 32;
    __shared__ unsigned short lA[64 * STR];
    __shared__ unsigned short lB[DOUT * STR];

    int tx = threadIdx.x;
    int base = blockIdx.x * 64;

    constexpr int CPM = DIN / 8;
    for (int c = tx; c < 64 * CPM; c += 256) {
        int n = c / CPM, o = (c - n * CPM) * 8;
        int node = base + n;
        uint4 vm = make_uint4(0, 0, 0, 0), vh = vm;
        if (node < NN) {
            vm = *(const uint4*)(magg + (size_t)node * DIN + o);
            vh = *(const uint4*)(h    + (size_t)node * DIN + o);
        }
        *(uint4*)(lA + n * STR + o)       = vm;
        *(uint4*)(lA + n * STR + DIN + o) = vh;
    }
    constexpr int CPW = K2 / 8;
    for (int c = tx; c < DOUT * CPW; c += 256) {
        int j = c / CPW, o = (c - j * CPW) * 8;
        *(uint4*)(lB + j * STR + o) = *(const uint4*)(Wt + (size_t)j * K2 + o);
    }
    __syncthreads();

    int lane = tx & 63;
    int wm = tx >> 6;
    int r16 = lane & 15, kg = lane >> 4;

    f32x4 acc[NT];
#pragma unroll
    for (int t = 0; t < NT; ++t) acc[t] = (f32x4){0.0f, 0.0f, 0.0f, 0.0f};

#pragma unroll
    for (int kk = 0; kk < KS; ++kk) {
        bf16x8 a = *(const bf16x8*)(lA + (wm * 16 + r16) * STR + kk * 32 + kg * 8);
#pragma unroll
        for (int t = 0; t < NT; ++t) {
            bf16x8 b = *(const bf16x8*)(lB + (t * 16 + r16) * STR + kk * 32 + kg * 8);
            acc[t] = __builtin_amdgcn_mfma_f32_16x16x32_bf16(a, b, acc[t], 0, 0, 0);
        }
    }

    if (!FINAL) {
#pragma unroll
        for (int t = 0; t < NT; ++t)
#pragma unroll
            for (int r = 0; r < 4; ++r) {
                int node = base + wm * 16 + kg * 4 + r;
                int colj = t * 16 + r16;
                float v = fmaxf(acc[t][r] + bl[colj], 0.0f);
                if (node < NN) hout[(size_t)node * DOUT + colj] = f2bs(v);
            }
    } else {
        __syncthreads();
        float* s4 = (float*)lB;
#pragma unroll
        for (int t = 0; t < NT; ++t)
#pragma unroll
            for (int r = 0; r < 4; ++r) {
                int nl = wm * 16 + kg * 4 + r;
                int colj = t * 16 + r16;
                s4[nl * 129 + colj] = fmaxf(acc[t][r] + bl[colj], 0.0f);
            }
        __syncthreads();
        int nl = tx >> 2, c = tx & 3;
        int node = base + nl;
        if (node < NN) {
            float a = bfi[c];
#pragma unroll 8
            for (int k = 0; k < 128; ++k)
                a = fmaf(s4[nl * 129 + k], Wf[k * 4 + c], a);
            out[(size_t)node * 4 + c] = 1.0f / (1.0f + expf(-a));
        }
    }
}

extern "C" void kernel_launch(void* const* d_in, const int* in_sizes, int n_in,
                              void* d_out, int out_size, void* d_ws, size_t ws_size,
                              hipStream_t stream) {
    const float* x   = (const float*)d_in[0];
    const int*   ei  = (const int*)d_in[1];
    const int*   src = ei;
    const int*   dst = ei + NE;
    const float* Wl0 = (const float*)d_in[2];
    const float* bl0 = (const float*)d_in[3];
    const float* Wr0 = (const float*)d_in[4];
    const float* Wl1 = (const float*)d_in[5];
    const float* bl1 = (const float*)d_in[6];
    const float* Wr1 = (const float*)d_in[7];
    const float* Wl2 = (const float*)d_in[8];
    const float* bl2 = (const float*)d_in[9];
    const float* Wr2 = (const float*)d_in[10];
    const float* Wl3 = (const float*)d_in[11];
    const float* bl3 = (const float*)d_in[12];
    const float* Wr3 = (const float*)d_in[13];
    const float* Wf  = (const float*)d_in[14];
    const float* bf  = (const float*)d_in[15];
    float* out = (float*)d_out;

    // ws (ints): row_ptr[NN+2] | bhist[512] | bcur[512] | col[NE] | pad -> 64B-aligned bf16 region
    size_t ints = (size_t)(NN + 2) + 512 + 512 + NE;   // 1,701,026
    ints = (ints + 15) & ~(size_t)15;                  // 1,701,040 -> *4 = 64B-aligned
    size_t need = ints * 4 + (size_t)NN * (96 + 32 + 64 + 96) * 2
                + (size_t)(64 * 64 + 96 * 128 + 128 * 192) * 2;
    if (ws_size < need) return;

    int* row_ptr = (int*)d_ws;
    int* bhist   = row_ptr + NN + 2;
    int* bcur    = bhist + 512;
    int* col     = bcur + 512;
    unsigned short* magg = (unsigned short*)((char*)d_ws + ints * 4);
    unsigned long long* ebuf = (unsigned long long*)magg;    // dead before magg is born
    unsigned short* h1   = magg + (size_t)NN * 96;
    unsigned short* h2   = h1 + (size_t)NN * 32;
    unsigned short* h3   = h2 + (size_t)NN * 64;
    unsigned short* wt1  = h3 + (size_t)NN * 96;
    unsigned short* wt2  = wt1 + 64 * 64;
    unsigned short* wt3  = wt2 + 96 * 128;

    // weight conversion (independent of CSR)
    wcvt_k<32, 64><<<(64 * 64 + 255) / 256, 256, 0, stream>>>(Wl1, Wr1, wt1);
    wcvt_k<64, 96><<<(96 * 128 + 255) / 256, 256, 0, stream>>>(Wl2, Wr2, wt2);
    wcvt_k<96, 128><<<(128 * 192 + 255) / 256, 256, 0, stream>>>(Wl3, Wr3, wt3);

    // CSR build
    hipMemsetAsync(bhist, 0, 512 * sizeof(int), stream);
    const int EB = (NE + 256 * RVPT - 1) / (256 * RVPT);
    bhist_k<<<EB, 256, 0, stream>>>(dst, bhist);
    bscan_k<<<1, 512, 0, stream>>>(bhist, bcur);
    reorder_k<<<EB, 256, 0, stream>>>(src, dst, bcur, ebuf);
    pcsr_k<<<BUCKETS, 256, 0, stream>>>(ebuf, bcur, row_ptr, col);

    const int AGRID = NN / 4;
    const int MG    = (NN + 63) / 64;

    // layer 0: x(3) -> h1(32)  (scalar, K=6)
    agg0_k<<<AGRID, 256, 0, stream>>>(row_ptr, col, x, magg);
    gemm_k<3, 32, 1, false, true><<<NN / 32, 256, 0, stream>>>(
        magg, x, Wl0, bl0, Wr0, nullptr, nullptr, h1, nullptr);

    // layer 1: h1(32) -> h2(64)
    agg_k<32, 4, 16><<<AGRID, 256, 0, stream>>>(row_ptr, col, h1, magg);
    mgemm_k<32, 64, false><<<MG, 256, 0, stream>>>(
        magg, h1, wt1, bl1, nullptr, nullptr, h2, nullptr);

    // layer 2: h2(64) -> h3(96)
    agg_k<64, 8, 8><<<AGRID, 256, 0, stream>>>(row_ptr, col, h2, magg);
    mgemm_k<64, 96, false><<<MG, 256, 0, stream>>>(
        magg, h2, wt2, bl2, nullptr, nullptr, h3, nullptr);

    // layer 3 + final: h3(96) -> [128] -> out(4)
    agg_k<96, 12, 5><<<AGRID, 256, 0, stream>>>(row_ptr, col, h3, magg);
    mgemm_k<96, 128, true><<<MG, 256, 0, stream>>>(
        magg, h3, wt3, bl3, Wf, bf, nullptr, out);
}